// Round 10
// baseline (266.461 us; speedup 1.0000x reference)
//
#include <hip/hip_runtime.h>

// ---------- common helpers ----------
typedef __bf16 bf16x8 __attribute__((ext_vector_type(8)));
typedef float f32x4 __attribute__((ext_vector_type(4)));

__device__ __forceinline__ float b2f(ushort u) {
    union { unsigned int i; float f; } v;
    v.i = ((unsigned int)u) << 16;
    return v.f;
}
__device__ __forceinline__ ushort f2b(float f) {
    union { float f; unsigned int i; } v;
    v.f = f;
    unsigned int x = v.i;
    unsigned int r = (x + 0x7fffu + ((x >> 16) & 1u)) >> 16;
    return (ushort)r;
}

#define D_MODEL 1024
#define D_INNER 2048
#define D_STATE 16
#define DT_RANK 64
#define NTOK    2048   // B*L
#define LSEQ    1024
#define NCH     32     // scan chunks
#define LC      32     // steps per chunk
#define KSL     16     // xproj K-slices

// ---------- K0: prep = RMSNorm (blocks 0..2047) + all weight cvts (blocks 2048+) ----------
__global__ __launch_bounds__(256) void prep_kernel(
    const float* __restrict__ hs, const float* __restrict__ w,
    ushort* __restrict__ hout, float* __restrict__ resid,
    const float* __restrict__ inproj, const float* __restrict__ outproj,
    const float* __restrict__ xprojw, const float* __restrict__ dtw,
    ushort* __restrict__ wIn, ushort* __restrict__ wOut,
    ushort* __restrict__ xpw, ushort* __restrict__ dtwb)
{
    int blk = blockIdx.x;
    int tid = threadIdx.x;
    if (blk < NTOK) {
        int t = blk;
        float4 r4 = *(const float4*)(hs + (size_t)t * D_MODEL + tid * 4);
        float s = r4.x * r4.x + r4.y * r4.y + r4.z * r4.z + r4.w * r4.w;
        #pragma unroll
        for (int off = 32; off >= 1; off >>= 1) s += __shfl_xor(s, off);
        __shared__ float red[4];
        int lane = tid & 63, wid = tid >> 6;
        if (lane == 0) red[wid] = s;
        __syncthreads();
        float tot = red[0] + red[1] + red[2] + red[3];
        float inv = 1.0f / (sqrtf(tot) * (1.0f / 32.0f) + 1e-5f);
        float4 w4 = *(const float4*)(w + tid * 4);
        ushort4 o;
        o.x = f2b(w4.x * r4.x * inv);
        o.y = f2b(w4.y * r4.y * inv);
        o.z = f2b(w4.z * r4.z * inv);
        o.w = f2b(w4.w * r4.w * inv);
        *(ushort4*)(hout + (size_t)t * D_MODEL + tid * 4) = o;
        *(float4*)(resid + (size_t)t * D_MODEL + tid * 4) = r4;   // exact copy
    } else {
        int i = (blk - NTOK) * 256 + tid;
        const float* src; ushort* dst; int off;
        if (i < 1048576)      { src = inproj;  dst = wIn;  off = i; }
        else if (i < 1572864) { src = outproj; dst = wOut; off = i - 1048576; }
        else if (i < 1622016) { src = xprojw;  dst = xpw;  off = i - 1572864; }
        else if (i < 1654784) { src = dtw;     dst = dtwb; off = i - 1622016; }
        else return;
        float4 v = *(const float4*)(src + (size_t)off * 4);
        ushort4 o;
        o.x = f2b(v.x); o.y = f2b(v.y); o.z = f2b(v.z); o.w = f2b(v.w);
        *(ushort4*)(dst + (size_t)off * 4) = o;
    }
}

// ---------- K2: xz GEMM 128x128, pipelined, bf16 out split into x/z halves ----------
__global__ __launch_bounds__(256) void gemm_xz_kernel(
    const ushort* __restrict__ Ag, const ushort* __restrict__ Wg,
    ushort* __restrict__ xq, ushort* __restrict__ zq, int K)
{
    __shared__ __align__(16) ushort sA[128 * 40];
    __shared__ __align__(16) ushort sB[128 * 40];
    int tid = threadIdx.x;
    int bm = blockIdx.x, bn = blockIdx.y;
    int wid = tid >> 6, lane = tid & 63;
    int wm = (wid >> 1) * 64, wn = (wid & 1) * 64;
    int l16 = lane & 15, q = lane >> 4;

    f32x4 acc[4][4];
    #pragma unroll
    for (int i = 0; i < 4; i++)
        #pragma unroll
        for (int j = 0; j < 4; j++)
            acc[i][j] = (f32x4){0.f, 0.f, 0.f, 0.f};

    const ushort* Abase = Ag + (size_t)bm * 128 * K;
    const ushort* Wbase = Wg + (size_t)bn * 128 * K;

    int r0 = tid >> 2, c0 = (tid & 3) << 3;
    const ushort* pA0 = Abase + (size_t)r0 * K + c0;
    const ushort* pA1 = Abase + (size_t)(r0 + 64) * K + c0;
    const ushort* pB0 = Wbase + (size_t)r0 * K + c0;
    const ushort* pB1 = Wbase + (size_t)(r0 + 64) * K + c0;

    uint4 pa0 = *(const uint4*)(pA0), pa1 = *(const uint4*)(pA1);
    uint4 pb0 = *(const uint4*)(pB0), pb1 = *(const uint4*)(pB1);

    for (int k0 = 0; k0 < K; k0 += 32) {
        *(uint4*)(sA + r0 * 40 + c0)        = pa0;
        *(uint4*)(sA + (r0 + 64) * 40 + c0) = pa1;
        *(uint4*)(sB + r0 * 40 + c0)        = pb0;
        *(uint4*)(sB + (r0 + 64) * 40 + c0) = pb1;
        __syncthreads();
        if (k0 + 32 < K) {
            pa0 = *(const uint4*)(pA0 + k0 + 32);
            pa1 = *(const uint4*)(pA1 + k0 + 32);
            pb0 = *(const uint4*)(pB0 + k0 + 32);
            pb1 = *(const uint4*)(pB1 + k0 + 32);
        }
        bf16x8 af[4], bfr[4];
        #pragma unroll
        for (int i = 0; i < 4; i++)
            af[i] = *(const bf16x8*)(sA + (wm + i * 16 + l16) * 40 + q * 8);
        #pragma unroll
        for (int j = 0; j < 4; j++)
            bfr[j] = *(const bf16x8*)(sB + (wn + j * 16 + l16) * 40 + q * 8);
        #pragma unroll
        for (int i = 0; i < 4; i++)
            #pragma unroll
            for (int j = 0; j < 4; j++)
                acc[i][j] = __builtin_amdgcn_mfma_f32_16x16x32_bf16(af[i], bfr[j], acc[i][j], 0, 0, 0);
        __syncthreads();
    }

    ushort* dst = (bn < 16) ? xq : zq;
    int row0 = bm * 128 + wm + q * 4;
    int col0 = (bn & 15) * 128 + wn + l16;
    #pragma unroll
    for (int i = 0; i < 4; i++)
        #pragma unroll
        for (int j = 0; j < 4; j++)
            #pragma unroll
            for (int r = 0; r < 4; r++)
                dst[(size_t)(row0 + i * 16 + r) * D_INNER + col0 + j * 16] =
                    f2b(acc[i][j][r]);
}

// ---------- K6: 64x64 MFMA GEMM, pipelined, f32 out ----------
__global__ __launch_bounds__(256) void gemm64_kernel(
    const ushort* __restrict__ Ag, const ushort* __restrict__ Wg,
    float* __restrict__ Cf, int M, int N, int K)
{
    __shared__ __align__(16) ushort sA[64 * 72];
    __shared__ __align__(16) ushort sB[64 * 72];
    int tid = threadIdx.x;
    int bm = blockIdx.x, bn = blockIdx.y;
    int wid = tid >> 6, lane = tid & 63;
    int wm = wid * 16;
    int l16 = lane & 15, q = lane >> 4;

    f32x4 acc[4];
    #pragma unroll
    for (int j = 0; j < 4; j++) acc[j] = (f32x4){0.f, 0.f, 0.f, 0.f};

    const ushort* Abase = Ag + (size_t)bm * 64 * K;
    const ushort* Wbase = Wg + (size_t)bn * 64 * K;

    int r0 = tid >> 3, c0 = (tid & 7) << 3;
    const ushort* pA0 = Abase + (size_t)r0 * K + c0;
    const ushort* pA1 = Abase + (size_t)(r0 + 32) * K + c0;
    const ushort* pB0 = Wbase + (size_t)r0 * K + c0;
    const ushort* pB1 = Wbase + (size_t)(r0 + 32) * K + c0;

    uint4 pa0 = *(const uint4*)(pA0), pa1 = *(const uint4*)(pA1);
    uint4 pb0 = *(const uint4*)(pB0), pb1 = *(const uint4*)(pB1);

    for (int k0 = 0; k0 < K; k0 += 64) {
        *(uint4*)(sA + r0 * 72 + c0)        = pa0;
        *(uint4*)(sA + (r0 + 32) * 72 + c0) = pa1;
        *(uint4*)(sB + r0 * 72 + c0)        = pb0;
        *(uint4*)(sB + (r0 + 32) * 72 + c0) = pb1;
        __syncthreads();
        if (k0 + 64 < K) {
            pa0 = *(const uint4*)(pA0 + k0 + 64);
            pa1 = *(const uint4*)(pA1 + k0 + 64);
            pb0 = *(const uint4*)(pB0 + k0 + 64);
            pb1 = *(const uint4*)(pB1 + k0 + 64);
        }
        #pragma unroll
        for (int ks = 0; ks < 2; ks++) {
            bf16x8 af = *(const bf16x8*)(sA + (wm + l16) * 72 + ks * 32 + q * 8);
            bf16x8 bfr[4];
            #pragma unroll
            for (int j = 0; j < 4; j++)
                bfr[j] = *(const bf16x8*)(sB + (j * 16 + l16) * 72 + ks * 32 + q * 8);
            #pragma unroll
            for (int j = 0; j < 4; j++)
                acc[j] = __builtin_amdgcn_mfma_f32_16x16x32_bf16(af, bfr[j], acc[j], 0, 0, 0);
        }
        __syncthreads();
    }

    int row0 = bm * 64 + wm + q * 4;
    int col0 = bn * 64 + l16;
    #pragma unroll
    for (int j = 0; j < 4; j++)
        #pragma unroll
        for (int r = 0; r < 4; r++)
            Cf[(size_t)(row0 + r) * N + col0 + j * 16] = acc[j][r];
}

// ---------- K4a-1: xproj split-K partial GEMM with fused conv+SiLU in A-staging ----------
__global__ __launch_bounds__(256) void xproj_partial_kernel(
    const ushort* __restrict__ xq, const float* __restrict__ cw,
    const float* __restrict__ cb, const ushort* __restrict__ wq,
    float* __restrict__ partials)
{
    __shared__ __align__(16) ushort sA[128 * 32];
    __shared__ __align__(16) ushort sB[96 * 32];
    int tid = threadIdx.x;
    int bm = blockIdx.x, sl = blockIdx.y;
    int wid = tid >> 6, lane = tid & 63;
    int wm = wid * 32;
    int l16 = lane & 15, q = lane >> 4;

    f32x4 acc[2][6];
    #pragma unroll
    for (int i = 0; i < 2; i++)
        #pragma unroll
        for (int j = 0; j < 6; j++)
            acc[i][j] = (f32x4){0.f, 0.f, 0.f, 0.f};

    int kbase = sl * (D_INNER / KSL);
    const uint4 zero4 = {0u, 0u, 0u, 0u};

    for (int kk = 0; kk < D_INNER / KSL; kk += 32) {
        int k0 = kbase + kk;
        __syncthreads();
        // stage A = silu(conv(x)) computed on the fly
        #pragma unroll
        for (int i = tid; i < 512; i += 256) {
            int r = i >> 2, c8 = (i & 3) << 3;
            int tok = bm * 128 + r;
            int l = tok & (LSEQ - 1);
            const ushort* xp = xq + (size_t)tok * D_INNER + k0 + c8;
            uint4 x3 = (l >= 3) ? *(const uint4*)(xp - 3 * D_INNER) : zero4;
            uint4 x2 = (l >= 2) ? *(const uint4*)(xp - 2 * D_INNER) : zero4;
            uint4 x1 = (l >= 1) ? *(const uint4*)(xp - 1 * D_INNER) : zero4;
            uint4 x0 = *(const uint4*)(xp);
            const ushort* t3 = (const ushort*)&x3;
            const ushort* t2 = (const ushort*)&x2;
            const ushort* t1 = (const ushort*)&x1;
            const ushort* t0 = (const ushort*)&x0;
            ushort outv[8];
            #pragma unroll
            for (int jj = 0; jj < 8; jj++) {
                int d = k0 + c8 + jj;
                float4 w4 = *(const float4*)(cw + d * 4);
                float a = cb[d] + b2f(t3[jj]) * w4.x + b2f(t2[jj]) * w4.y
                                + b2f(t1[jj]) * w4.z + b2f(t0[jj]) * w4.w;
                outv[jj] = f2b(a / (1.f + __expf(-a)));
            }
            *(uint4*)(sA + i * 8) = *(const uint4*)outv;
        }
        for (int i = tid; i < 384; i += 256) {
            int r = i >> 2, c = (i & 3) << 3;
            *(uint4*)(sB + i * 8) = *(const uint4*)(wq + (size_t)r * D_INNER + k0 + c);
        }
        __syncthreads();
        bf16x8 af[2], bfr[6];
        #pragma unroll
        for (int i = 0; i < 2; i++)
            af[i] = *(const bf16x8*)(sA + (wm + i * 16 + l16) * 32 + q * 8);
        #pragma unroll
        for (int j = 0; j < 6; j++)
            bfr[j] = *(const bf16x8*)(sB + (j * 16 + l16) * 32 + q * 8);
        #pragma unroll
        for (int i = 0; i < 2; i++)
            #pragma unroll
            for (int j = 0; j < 6; j++)
                acc[i][j] = __builtin_amdgcn_mfma_f32_16x16x32_bf16(af[i], bfr[j], acc[i][j], 0, 0, 0);
    }

    float* out = partials + (size_t)sl * NTOK * 96;
    int row0 = bm * 128 + wm + q * 4;
    #pragma unroll
    for (int i = 0; i < 2; i++)
        #pragma unroll
        for (int j = 0; j < 6; j++)
            #pragma unroll
            for (int r = 0; r < 4; r++)
                out[(size_t)(row0 + i * 16 + r) * 96 + j * 16 + l16] = acc[i][j][r];
}

// ---------- K4a-2: xproj reduce (sum 16 partials) ----------
__global__ __launch_bounds__(256) void xproj_reduce_kernel(
    const float* __restrict__ partials, float* __restrict__ xdbl,
    ushort* __restrict__ xdbl64)
{
    int idx = blockIdx.x * 256 + threadIdx.x;    // 196608 outputs
    float s = 0.f;
    #pragma unroll
    for (int sl = 0; sl < KSL; sl++)
        s += partials[(size_t)sl * NTOK * 96 + idx];
    xdbl[idx] = s;
    int col = idx % 96;
    if (col < DT_RANK)
        xdbl64[(size_t)(idx / 96) * DT_RANK + col] = f2b(s);
}

// ---------- K4b: dt = softplus(xdbl64 @ dt_proj_w^T + b) -> bf16, coalesced ----------
__global__ __launch_bounds__(256) void dt_gemm_kernel(
    const ushort* __restrict__ xd64, const ushort* __restrict__ dtwq,
    const float* __restrict__ dtb, ushort* __restrict__ dtout)
{
    __shared__ __align__(16) ushort sA[64 * 72];
    __shared__ __align__(16) ushort sB[64 * 72];
    int tid = threadIdx.x;
    int bm = blockIdx.x, bn = blockIdx.y;
    int wid = tid >> 6, lane = tid & 63;
    int wm = wid * 16;
    int l16 = lane & 15, q = lane >> 4;

    const ushort* Abase = xd64 + (size_t)bm * 64 * DT_RANK;
    const ushort* Bbase = dtwq + (size_t)bn * 64 * DT_RANK;
    #pragma unroll
    for (int i = tid; i < 512; i += 256) {
        int r = i >> 3, c = (i & 7) << 3;
        *(uint4*)(sA + r * 72 + c) = *(const uint4*)(Abase + (size_t)r * DT_RANK + c);
        *(uint4*)(sB + r * 72 + c) = *(const uint4*)(Bbase + (size_t)r * DT_RANK + c);
    }
    __syncthreads();

    f32x4 acc[4];
    #pragma unroll
    for (int j = 0; j < 4; j++) acc[j] = (f32x4){0.f, 0.f, 0.f, 0.f};

    #pragma unroll
    for (int ks = 0; ks < 2; ks++) {
        bf16x8 af = *(const bf16x8*)(sA + (wm + l16) * 72 + ks * 32 + q * 8);
        bf16x8 bfr[4];
        #pragma unroll
        for (int j = 0; j < 4; j++)
            bfr[j] = *(const bf16x8*)(sB + (j * 16 + l16) * 72 + ks * 32 + q * 8);
        #pragma unroll
        for (int j = 0; j < 4; j++)
            acc[j] = __builtin_amdgcn_mfma_f32_16x16x32_bf16(af, bfr[j], acc[j], 0, 0, 0);
    }

    __syncthreads();
    #pragma unroll
    for (int j = 0; j < 4; j++) {
        float bias = dtb[bn * 64 + j * 16 + l16];
        #pragma unroll
        for (int r = 0; r < 4; r++) {
            float s = acc[j][r] + bias;
            float sp = (s > 20.f) ? s : log1pf(__expf(s));
            sA[(wm + q * 4 + r) * 72 + j * 16 + l16] = f2b(sp);
        }
    }
    __syncthreads();
    int row0 = bm * 64, col0 = bn * 64;
    #pragma unroll
    for (int rep = 0; rep < 2; rep++) {
        int off = rep * 2048 + tid * 8;
        int row = off >> 6, col = off & 63;
        *(uint4*)(dtout + (size_t)(row0 + row) * D_INNER + col0 + col) =
            *(const uint4*)(sA + row * 72 + col);
    }
}

// ---------- K5a: scan pass A — lane-owns-d, sliding-window conv fused ----------
__global__ __launch_bounds__(256) void scan_partA_kernel(
    const ushort* __restrict__ dt, const ushort* __restrict__ xq,
    const float* __restrict__ cw, const float* __restrict__ cb,
    const float* __restrict__ xdbl, const float* __restrict__ Alog,
    float2* __restrict__ ch1, float2* __restrict__ ch2)
{
    __shared__ float sBC[LC][32];
    int bid = blockIdx.x;
    int g = bid & 7;
    int c = (bid >> 3) & (NCH - 1);
    int b = bid >> 8;
    int tid = threadIdx.x;
    int lane = tid & 63, wid = tid >> 6;
    int d = g * 256 + wid * 64 + lane;
    int l0 = c * LC;

    {   // stage B/C tile
        int r = tid >> 3, c4 = (tid & 7) * 4;
        *(float4*)&sBC[r][c4] =
            *(const float4*)(xdbl + ((size_t)(b * LSEQ + l0 + r)) * 96 + 64 + c4);
    }
    float A[16];
    #pragma unroll
    for (int k = 0; k < 4; k++)
        *(float4*)&A[k * 4] = *(const float4*)(Alog + d * D_STATE + k * 4);
    #pragma unroll
    for (int n = 0; n < 16; n++) A[n] = -__expf(A[n]);
    float4 w4 = *(const float4*)(cw + d * 4);
    float cbv = cb[d];
    __syncthreads();

    const ushort* dtp = dt + ((size_t)(b * LSEQ + l0)) * D_INNER + d;
    const ushort* xp  = xq + ((size_t)(b * LSEQ + l0)) * D_INNER + d;

    float xm3 = 0.f, xm2 = 0.f, xm1 = 0.f;
    if (c > 0) {                                  // l0 >= 32 -> all taps in range
        xm3 = b2f(xp[-3 * D_INNER]);
        xm2 = b2f(xp[-2 * D_INNER]);
        xm1 = b2f(xp[-1 * D_INNER]);
    }

    float h[16], ap[16];
    #pragma unroll
    for (int n = 0; n < 16; n++) { h[n] = 0.f; ap[n] = 1.f; }

    for (int l = 0; l < LC; l++) {
        float dtv = b2f(dtp[(size_t)l * D_INNER]);
        float xcur = b2f(xp[(size_t)l * D_INNER]);
        float cv = cbv + xm3 * w4.x + xm2 * w4.y + xm1 * w4.z + xcur * w4.w;
        float xcv = cv / (1.f + __expf(-cv));
        xm3 = xm2; xm2 = xm1; xm1 = xcur;
        float t = dtv * xcv;
        float Bv[16];
        #pragma unroll
        for (int k = 0; k < 4; k++)
            *(float4*)&Bv[k * 4] = *(const float4*)&sBC[l][k * 4];
        #pragma unroll
        for (int n = 0; n < 16; n++) {
            float a = __expf(dtv * A[n]);
            h[n] = h[n] * a + t * Bv[n];
            ap[n] *= a;
        }
    }

    float2* outp = (c < 16 ? ch1 : ch2) +
                   ((size_t)((b * 16 + (c & 15)) * D_INNER + d)) * D_STATE;
    #pragma unroll
    for (int n = 0; n < 16; n += 2) {
        float4 v = {ap[n], h[n], ap[n + 1], h[n + 1]};
        *(float4*)&outp[n] = v;
    }
}

// ---------- K5b: stitch (in-place: .x becomes h_init for that chunk) ----------
__global__ __launch_bounds__(256) void scan_partB_kernel(
    float2* __restrict__ ch1, float2* __restrict__ ch2)
{
    int kk = blockIdx.x * 256 + threadIdx.x;   // 65536 = b(2) x d(2048) x n(16)
    int b = kk >> 15, dn = kk & 32767;
    float run = 0.f;
    #pragma unroll
    for (int c = 0; c < NCH; c++) {
        float2* p = (c < 16 ? ch1 : ch2) +
                    (size_t)(b * 16 + (c & 15)) * 32768 + dn;
        float2 v = *p;
        p->x = run;                 // h_init entering chunk c
        run = v.x * run + v.y;
    }
}

// ---------- K5c: scan pass C — sliding-window conv + C-proj + D-skip + gate ----------
__global__ __launch_bounds__(256) void scan_partC_kernel(
    const ushort* __restrict__ dt, const ushort* __restrict__ xq,
    const float* __restrict__ cw, const float* __restrict__ cb,
    const float* __restrict__ xdbl, const ushort* __restrict__ zq,
    const float* __restrict__ Alog, const float* __restrict__ Dp,
    const float2* __restrict__ ch1, const float2* __restrict__ ch2,
    ushort* __restrict__ yg)
{
    __shared__ float sBC[LC][32];
    int bid = blockIdx.x;
    int g = bid & 7;
    int c = (bid >> 3) & (NCH - 1);
    int b = bid >> 8;
    int tid = threadIdx.x;
    int lane = tid & 63, wid = tid >> 6;
    int d = g * 256 + wid * 64 + lane;
    int l0 = c * LC;

    {
        int r = tid >> 3, c4 = (tid & 7) * 4;
        *(float4*)&sBC[r][c4] =
            *(const float4*)(xdbl + ((size_t)(b * LSEQ + l0 + r)) * 96 + 64 + c4);
    }
    float A[16];
    #pragma unroll
    for (int k = 0; k < 4; k++)
        *(float4*)&A[k * 4] = *(const float4*)(Alog + d * D_STATE + k * 4);
    #pragma unroll
    for (int n = 0; n < 16; n++) A[n] = -__expf(A[n]);
    float Dd = Dp[d];
    float4 w4 = *(const float4*)(cw + d * 4);
    float cbv = cb[d];

    const float2* hip_ = (c < 16 ? ch1 : ch2) +
                         ((size_t)((b * 16 + (c & 15)) * D_INNER + d)) * D_STATE;
    float h[16];
    #pragma unroll
    for (int n = 0; n < 16; n += 2) {
        float4 v = *(const float4*)&hip_[n];
        h[n] = v.x; h[n + 1] = v.z;
    }
    __syncthreads();

    const ushort* dtp = dt + ((size_t)(b * LSEQ + l0)) * D_INNER + d;
    const ushort* xp  = xq + ((size_t)(b * LSEQ + l0)) * D_INNER + d;
    const ushort* zp  = zq + ((size_t)(b * LSEQ + l0)) * D_INNER + d;
    ushort* yp = yg + ((size_t)(b * LSEQ + l0)) * D_INNER + d;

    float xm3 = 0.f, xm2 = 0.f, xm1 = 0.f;
    if (c > 0) {
        xm3 = b2f(xp[-3 * D_INNER]);
        xm2 = b2f(xp[-2 * D_INNER]);
        xm1 = b2f(xp[-1 * D_INNER]);
    }

    for (int l = 0; l < LC; l++) {
        float dtv = b2f(dtp[(size_t)l * D_INNER]);
        float xcur = b2f(xp[(size_t)l * D_INNER]);
        float zv  = b2f(zp[(size_t)l * D_INNER]);
        float cv = cbv + xm3 * w4.x + xm2 * w4.y + xm1 * w4.z + xcur * w4.w;
        float xcv = cv / (1.f + __expf(-cv));
        xm3 = xm2; xm2 = xm1; xm1 = xcur;
        float t = dtv * xcv;
        float Bv[16], Cv[16];
        #pragma unroll
        for (int k = 0; k < 4; k++) {
            *(float4*)&Bv[k * 4] = *(const float4*)&sBC[l][k * 4];
            *(float4*)&Cv[k * 4] = *(const float4*)&sBC[l][16 + k * 4];
        }
        float p0 = 0.f, p1 = 0.f, p2 = 0.f, p3 = 0.f;
        #pragma unroll
        for (int n = 0; n < 16; n += 4) {
            float a0 = __expf(dtv * A[n]);
            float a1 = __expf(dtv * A[n + 1]);
            float a2 = __expf(dtv * A[n + 2]);
            float a3 = __expf(dtv * A[n + 3]);
            h[n]     = h[n] * a0 + t * Bv[n];
            h[n + 1] = h[n + 1] * a1 + t * Bv[n + 1];
            h[n + 2] = h[n + 2] * a2 + t * Bv[n + 2];
            h[n + 3] = h[n + 3] * a3 + t * Bv[n + 3];
            p0 += h[n] * Cv[n];
            p1 += h[n + 1] * Cv[n + 1];
            p2 += h[n + 2] * Cv[n + 2];
            p3 += h[n + 3] * Cv[n + 3];
        }
        float p = (p0 + p1) + (p2 + p3);
        float y = p + Dd * xcv;
        float sz = zv / (1.f + __expf(-zv));
        yp[(size_t)l * D_INNER] = f2b(y * sz);
    }
}

extern "C" void kernel_launch(void* const* d_in, const int* in_sizes, int n_in,
                              void* d_out, int out_size, void* d_ws, size_t ws_size,
                              hipStream_t stream)
{
    const float* hs      = (const float*)d_in[0];
    const float* norm_w  = (const float*)d_in[1];
    const float* inproj  = (const float*)d_in[2];
    const float* convw   = (const float*)d_in[3];
    const float* convb   = (const float*)d_in[4];
    const float* xprojw  = (const float*)d_in[5];
    const float* dtw     = (const float*)d_in[6];
    const float* dtb     = (const float*)d_in[7];
    const float* alog    = (const float*)d_in[8];
    const float* dvec    = (const float*)d_in[9];
    const float* outproj = (const float*)d_in[10];

    float* out_main  = (float*)d_out;                        // (B,L,D_MODEL) f32
    float* out_resid = (float*)d_out + (size_t)NTOK * D_MODEL;

    // all buffers disjoint
    char* ws = (char*)d_ws;
    ushort* xq      = (ushort*)(ws);                         // 8.4MB x-half bf16
    ushort* zq      = (ushort*)(ws +  9437184);              // 8.4MB z-half bf16
    ushort* dtq     = (ushort*)(ws + 18874368);              // 8.4MB dt bf16
    float2* ch1     = (float2*)(ws + 28311552);              // 8.4MB chunks 0..15
    float2* ch2     = (float2*)(ws + 37748736);              // 8.4MB chunks 16..31
    float*  xdbl    = (float*) (ws + 47185920);              // 768KB
    ushort* xd64    = (ushort*)(ws + 48234496);              // 256KB
    ushort* xpw_b   = (ushort*)(ws + 48758784);              // 384KB
    ushort* dtw_b   = (ushort*)(ws + 49283072);              // 256KB
    ushort* wIn     = (ushort*)(ws + 50331648);              // 8.4MB
    ushort* wOut    = (ushort*)(ws + 59768832);              // 4.2MB
    ushort* h_bf16  = (ushort*)(ws + 65011712);              // 4.2MB
    float*  xprojP  = (float*) (ws + 70254592);              // 12.6MB partials (dead after reduce)
    ushort* yg_bf16 = (ushort*)(ws + 83886080);              // 8.4MB

    // K0: prep = rmsnorm + all weight conversions (one launch)
    prep_kernel<<<NTOK + 6464, 256, 0, stream>>>(
        hs, norm_w, h_bf16, out_resid,
        inproj, outproj, xprojw, dtw, wIn, wOut, xpw_b, dtw_b);

    // K2: xz GEMM -> bf16 x/z halves
    gemm_xz_kernel<<<dim3(NTOK / 128, (2 * D_INNER) / 128), 256, 0, stream>>>(
        h_bf16, wIn, xq, zq, D_MODEL);

    // K4a: x_dbl GEMM (conv fused into A-staging) — split-K partials then reduce
    xproj_partial_kernel<<<dim3(NTOK / 128, KSL), 256, 0, stream>>>(
        xq, convw, convb, xpw_b, xprojP);
    xproj_reduce_kernel<<<NTOK * 96 / 256, 256, 0, stream>>>(xprojP, xdbl, xd64);

    // K4b: dt GEMM + bias + softplus -> bf16
    dt_gemm_kernel<<<dim3(NTOK / 64, D_INNER / 64), 256, 0, stream>>>(
        xd64, dtw_b, dtb, dtq);

    // K5: chunked parallel scan, lane-owns-d, conv fused (sliding window)
    scan_partA_kernel<<<512, 256, 0, stream>>>(dtq, xq, convw, convb, xdbl, alog, ch1, ch2);
    scan_partB_kernel<<<256, 256, 0, stream>>>(ch1, ch2);
    scan_partC_kernel<<<512, 256, 0, stream>>>(dtq, xq, convw, convb, xdbl, zq,
                                               alog, dvec, ch1, ch2, yg_bf16);

    // K6: out = yg @ out_proj_w^T -> f32
    gemm64_kernel<<<dim3(NTOK / 64, D_MODEL / 64), 256, 0, stream>>>(
        yg_bf16, wOut, out_main, NTOK, D_MODEL, D_INNER);
}

// Round 11
// 262.698 us; speedup vs baseline: 1.0143x; 1.0143x over previous
//
#include <hip/hip_runtime.h>

// ---------- common helpers ----------
typedef __bf16 bf16x8 __attribute__((ext_vector_type(8)));
typedef float f32x4 __attribute__((ext_vector_type(4)));

__device__ __forceinline__ float b2f(ushort u) {
    union { unsigned int i; float f; } v;
    v.i = ((unsigned int)u) << 16;
    return v.f;
}
__device__ __forceinline__ ushort f2b(float f) {
    union { float f; unsigned int i; } v;
    v.f = f;
    unsigned int x = v.i;
    unsigned int r = (x + 0x7fffu + ((x >> 16) & 1u)) >> 16;
    return (ushort)r;
}
// async 16B global->LDS (gfx950 global_load_lds_dwordx4). lds ptr must be wave-uniform;
// lane i lands at lds + i*16B.
__device__ __forceinline__ void gload16(const ushort* g, ushort* l) {
    __builtin_amdgcn_global_load_lds(
        (const __attribute__((address_space(1))) unsigned int*)g,
        (__attribute__((address_space(3))) unsigned int*)l, 16, 0, 0);
}
// LDS fragment read with XOR chunk swizzle (row stride 64 ushorts, 8 chunks of 8)
__device__ __forceinline__ bf16x8 ldsfrag(const ushort* s, int row, int cq) {
    int p = cq ^ (row & 7);
    return *(const bf16x8*)(s + row * 64 + p * 8);
}

#define D_MODEL 1024
#define D_INNER 2048
#define D_STATE 16
#define DT_RANK 64
#define NTOK    2048   // B*L
#define LSEQ    1024
#define NCH     32     // scan chunks
#define LC      32     // steps per chunk
#define KSL     16     // xproj K-slices

// ---------- K0: prep = RMSNorm (blocks 0..2047) + all weight cvts (blocks 2048+) ----------
__global__ __launch_bounds__(256) void prep_kernel(
    const float* __restrict__ hs, const float* __restrict__ w,
    ushort* __restrict__ hout, float* __restrict__ resid,
    const float* __restrict__ inproj, const float* __restrict__ outproj,
    const float* __restrict__ xprojw, const float* __restrict__ dtw,
    ushort* __restrict__ wIn, ushort* __restrict__ wOut,
    ushort* __restrict__ xpw, ushort* __restrict__ dtwb)
{
    int blk = blockIdx.x;
    int tid = threadIdx.x;
    if (blk < NTOK) {
        int t = blk;
        float4 r4 = *(const float4*)(hs + (size_t)t * D_MODEL + tid * 4);
        float s = r4.x * r4.x + r4.y * r4.y + r4.z * r4.z + r4.w * r4.w;
        #pragma unroll
        for (int off = 32; off >= 1; off >>= 1) s += __shfl_xor(s, off);
        __shared__ float red[4];
        int lane = tid & 63, wid = tid >> 6;
        if (lane == 0) red[wid] = s;
        __syncthreads();
        float tot = red[0] + red[1] + red[2] + red[3];
        float inv = 1.0f / (sqrtf(tot) * (1.0f / 32.0f) + 1e-5f);
        float4 w4 = *(const float4*)(w + tid * 4);
        ushort4 o;
        o.x = f2b(w4.x * r4.x * inv);
        o.y = f2b(w4.y * r4.y * inv);
        o.z = f2b(w4.z * r4.z * inv);
        o.w = f2b(w4.w * r4.w * inv);
        *(ushort4*)(hout + (size_t)t * D_MODEL + tid * 4) = o;
        *(float4*)(resid + (size_t)t * D_MODEL + tid * 4) = r4;   // exact copy
    } else {
        int i = (blk - NTOK) * 256 + tid;
        const float* src; ushort* dst; int off;
        if (i < 1048576)      { src = inproj;  dst = wIn;  off = i; }
        else if (i < 1572864) { src = outproj; dst = wOut; off = i - 1048576; }
        else if (i < 1622016) { src = xprojw;  dst = xpw;  off = i - 1572864; }
        else if (i < 1654784) { src = dtw;     dst = dtwb; off = i - 1622016; }
        else return;
        float4 v = *(const float4*)(src + (size_t)off * 4);
        ushort4 o;
        o.x = f2b(v.x); o.y = f2b(v.y); o.z = f2b(v.z); o.w = f2b(v.w);
        *(ushort4*)(dst + (size_t)off * 4) = o;
    }
}

// ---------- K2: xz GEMM 128x128, BK=64, async global_load_lds + XOR-swizzled LDS ----------
__global__ __launch_bounds__(256) void gemm_xz_kernel(
    const ushort* __restrict__ Ag, const ushort* __restrict__ Wg,
    ushort* __restrict__ xq, ushort* __restrict__ zq, int K)
{
    __shared__ __align__(16) ushort sA[128 * 64];   // 16KB
    __shared__ __align__(16) ushort sB[128 * 64];   // 16KB
    int tid = threadIdx.x;
    int bm = blockIdx.x, bn = blockIdx.y;
    int wid = tid >> 6, lane = tid & 63;
    int wm = (wid >> 1) * 64, wn = (wid & 1) * 64;
    int l16 = lane & 15, q = lane >> 4;

    f32x4 acc[4][4];
    #pragma unroll
    for (int i = 0; i < 4; i++)
        #pragma unroll
        for (int j = 0; j < 4; j++)
            acc[i][j] = (f32x4){0.f, 0.f, 0.f, 0.f};

    const ushort* Abase = Ag + (size_t)bm * 128 * K;
    const ushort* Wbase = Wg + (size_t)bn * 128 * K;

    // staging: 16 segments of 8 rows x 128B per matrix; wave w handles segs w*4..w*4+3
    // lane i in segment s: row = s*8 + (i>>3), global chunk gc = (i&7) ^ (row&7)
    int segr = lane >> 3, segc = lane & 7;
    size_t goff[4]; int sseg[4];
    #pragma unroll
    for (int t = 0; t < 4; t++) {
        int s = wid * 4 + t;
        int r = s * 8 + segr;
        int gc = segc ^ (r & 7);
        sseg[t] = s * 512;
        goff[t] = (size_t)r * K + gc * 8;
    }

    for (int k0 = 0; k0 < K; k0 += 64) {
        __syncthreads();
        #pragma unroll
        for (int t = 0; t < 4; t++) {
            gload16(Abase + goff[t] + k0, sA + sseg[t]);
            gload16(Wbase + goff[t] + k0, sB + sseg[t]);
        }
        __syncthreads();
        #pragma unroll
        for (int ks = 0; ks < 2; ks++) {
            int cq = ks * 4 + q;
            bf16x8 af[4], bfr[4];
            #pragma unroll
            for (int i = 0; i < 4; i++)
                af[i] = ldsfrag(sA, wm + i * 16 + l16, cq);
            #pragma unroll
            for (int j = 0; j < 4; j++)
                bfr[j] = ldsfrag(sB, wn + j * 16 + l16, cq);
            #pragma unroll
            for (int i = 0; i < 4; i++)
                #pragma unroll
                for (int j = 0; j < 4; j++)
                    acc[i][j] = __builtin_amdgcn_mfma_f32_16x16x32_bf16(af[i], bfr[j], acc[i][j], 0, 0, 0);
        }
    }

    ushort* dst = (bn < 16) ? xq : zq;
    int row0 = bm * 128 + wm + q * 4;
    int col0 = (bn & 15) * 128 + wn + l16;
    #pragma unroll
    for (int i = 0; i < 4; i++)
        #pragma unroll
        for (int j = 0; j < 4; j++)
            #pragma unroll
            for (int r = 0; r < 4; r++)
                dst[(size_t)(row0 + i * 16 + r) * D_INNER + col0 + j * 16] =
                    f2b(acc[i][j][r]);
}

// ---------- K6: 64x64 GEMM, BK=64, async global_load_lds + XOR-swizzled LDS ----------
__global__ __launch_bounds__(256) void gemm64_kernel(
    const ushort* __restrict__ Ag, const ushort* __restrict__ Wg,
    float* __restrict__ Cf, int M, int N, int K)
{
    __shared__ __align__(16) ushort sA[64 * 64];    // 8KB
    __shared__ __align__(16) ushort sB[64 * 64];
    int tid = threadIdx.x;
    int bm = blockIdx.x, bn = blockIdx.y;
    int wid = tid >> 6, lane = tid & 63;
    int wm = wid * 16;
    int l16 = lane & 15, q = lane >> 4;

    f32x4 acc[4];
    #pragma unroll
    for (int j = 0; j < 4; j++) acc[j] = (f32x4){0.f, 0.f, 0.f, 0.f};

    const ushort* Abase = Ag + (size_t)bm * 64 * K;
    const ushort* Wbase = Wg + (size_t)bn * 64 * K;

    // 8 segments of 8 rows per matrix; wave w handles segs {2w, 2w+1}
    int segr = lane >> 3, segc = lane & 7;
    size_t goff[2]; int sseg[2];
    #pragma unroll
    for (int t = 0; t < 2; t++) {
        int s = wid * 2 + t;
        int r = s * 8 + segr;
        int gc = segc ^ (r & 7);
        sseg[t] = s * 512;
        goff[t] = (size_t)r * K + gc * 8;
    }

    for (int k0 = 0; k0 < K; k0 += 64) {
        __syncthreads();
        #pragma unroll
        for (int t = 0; t < 2; t++) {
            gload16(Abase + goff[t] + k0, sA + sseg[t]);
            gload16(Wbase + goff[t] + k0, sB + sseg[t]);
        }
        __syncthreads();
        #pragma unroll
        for (int ks = 0; ks < 2; ks++) {
            int cq = ks * 4 + q;
            bf16x8 af = ldsfrag(sA, wm + l16, cq);
            bf16x8 bfr[4];
            #pragma unroll
            for (int j = 0; j < 4; j++)
                bfr[j] = ldsfrag(sB, j * 16 + l16, cq);
            #pragma unroll
            for (int j = 0; j < 4; j++)
                acc[j] = __builtin_amdgcn_mfma_f32_16x16x32_bf16(af, bfr[j], acc[j], 0, 0, 0);
        }
    }

    int row0 = bm * 64 + wm + q * 4;
    int col0 = bn * 64 + l16;
    #pragma unroll
    for (int j = 0; j < 4; j++)
        #pragma unroll
        for (int r = 0; r < 4; r++)
            Cf[(size_t)(row0 + r) * N + col0 + j * 16] = acc[j][r];
}

// ---------- K3: causal depthwise conv (4 taps) + SiLU, bf16 in/out ----------
__global__ __launch_bounds__(256) void conv_silu_kernel(
    const ushort* __restrict__ xq, const float* __restrict__ cw,
    const float* __restrict__ cb, ushort* __restrict__ xcb)
{
    int idx = blockIdx.x * 256 + threadIdx.x;     // (token, d) flat
    int d = idx & (D_INNER - 1);
    int t = idx >> 11;
    int l = t & (LSEQ - 1), b = t >> 10;
    float4 w4 = *(const float4*)(cw + d * 4);
    float acc = cb[d];
    float wk[4] = {w4.x, w4.y, w4.z, w4.w};
    #pragma unroll
    for (int k = 0; k < 4; k++) {
        int ll = l - 3 + k;
        float xv = (ll >= 0) ? b2f(xq[(((size_t)(b * LSEQ + ll)) << 11) + d]) : 0.f;
        acc += xv * wk[k];
    }
    float sg = acc / (1.f + __expf(-acc));
    xcb[idx] = f2b(sg);
}

// ---------- K4a-1: xproj split-K partial GEMM ----------
__global__ __launch_bounds__(256) void xproj_partial_kernel(
    const ushort* __restrict__ xcb, const ushort* __restrict__ wq,
    float* __restrict__ partials)
{
    __shared__ __align__(16) ushort sA[128 * 32];
    __shared__ __align__(16) ushort sB[96 * 32];
    int tid = threadIdx.x;
    int bm = blockIdx.x, sl = blockIdx.y;
    int wid = tid >> 6, lane = tid & 63;
    int wm = wid * 32;
    int l16 = lane & 15, q = lane >> 4;

    f32x4 acc[2][6];
    #pragma unroll
    for (int i = 0; i < 2; i++)
        #pragma unroll
        for (int j = 0; j < 6; j++)
            acc[i][j] = (f32x4){0.f, 0.f, 0.f, 0.f};

    const ushort* Abase = xcb + (size_t)bm * 128 * D_INNER;
    int kbase = sl * (D_INNER / KSL);

    for (int kk = 0; kk < D_INNER / KSL; kk += 32) {
        int k0 = kbase + kk;
        __syncthreads();
        #pragma unroll
        for (int i = tid; i < 512; i += 256) {
            int r = i >> 2, c = (i & 3) << 3;
            *(uint4*)(sA + i * 8) = *(const uint4*)(Abase + (size_t)r * D_INNER + k0 + c);
        }
        for (int i = tid; i < 384; i += 256) {
            int r = i >> 2, c = (i & 3) << 3;
            *(uint4*)(sB + i * 8) = *(const uint4*)(wq + (size_t)r * D_INNER + k0 + c);
        }
        __syncthreads();
        bf16x8 af[2], bfr[6];
        #pragma unroll
        for (int i = 0; i < 2; i++)
            af[i] = *(const bf16x8*)(sA + (wm + i * 16 + l16) * 32 + q * 8);
        #pragma unroll
        for (int j = 0; j < 6; j++)
            bfr[j] = *(const bf16x8*)(sB + (j * 16 + l16) * 32 + q * 8);
        #pragma unroll
        for (int i = 0; i < 2; i++)
            #pragma unroll
            for (int j = 0; j < 6; j++)
                acc[i][j] = __builtin_amdgcn_mfma_f32_16x16x32_bf16(af[i], bfr[j], acc[i][j], 0, 0, 0);
    }

    float* out = partials + (size_t)sl * NTOK * 96;
    int row0 = bm * 128 + wm + q * 4;
    #pragma unroll
    for (int i = 0; i < 2; i++)
        #pragma unroll
        for (int j = 0; j < 6; j++)
            #pragma unroll
            for (int r = 0; r < 4; r++)
                out[(size_t)(row0 + i * 16 + r) * 96 + j * 16 + l16] = acc[i][j][r];
}

// ---------- K4a-2: xproj reduce (sum 16 partials) ----------
__global__ __launch_bounds__(256) void xproj_reduce_kernel(
    const float* __restrict__ partials, float* __restrict__ xdbl,
    ushort* __restrict__ xdbl64)
{
    int idx = blockIdx.x * 256 + threadIdx.x;    // 196608 outputs
    float s = 0.f;
    #pragma unroll
    for (int sl = 0; sl < KSL; sl++)
        s += partials[(size_t)sl * NTOK * 96 + idx];
    xdbl[idx] = s;
    int col = idx % 96;
    if (col < DT_RANK)
        xdbl64[(size_t)(idx / 96) * DT_RANK + col] = f2b(s);
}

// ---------- K4b: dt = softplus(xdbl64 @ dt_proj_w^T + b) -> bf16, coalesced ----------
__global__ __launch_bounds__(256) void dt_gemm_kernel(
    const ushort* __restrict__ xd64, const ushort* __restrict__ dtwq,
    const float* __restrict__ dtb, ushort* __restrict__ dtout)
{
    __shared__ __align__(16) ushort sA[64 * 72];
    __shared__ __align__(16) ushort sB[64 * 72];
    int tid = threadIdx.x;
    int bm = blockIdx.x, bn = blockIdx.y;
    int wid = tid >> 6, lane = tid & 63;
    int wm = wid * 16;
    int l16 = lane & 15, q = lane >> 4;

    const ushort* Abase = xd64 + (size_t)bm * 64 * DT_RANK;
    const ushort* Bbase = dtwq + (size_t)bn * 64 * DT_RANK;
    #pragma unroll
    for (int i = tid; i < 512; i += 256) {
        int r = i >> 3, c = (i & 7) << 3;
        *(uint4*)(sA + r * 72 + c) = *(const uint4*)(Abase + (size_t)r * DT_RANK + c);
        *(uint4*)(sB + r * 72 + c) = *(const uint4*)(Bbase + (size_t)r * DT_RANK + c);
    }
    __syncthreads();

    f32x4 acc[4];
    #pragma unroll
    for (int j = 0; j < 4; j++) acc[j] = (f32x4){0.f, 0.f, 0.f, 0.f};

    #pragma unroll
    for (int ks = 0; ks < 2; ks++) {
        bf16x8 af = *(const bf16x8*)(sA + (wm + l16) * 72 + ks * 32 + q * 8);
        bf16x8 bfr[4];
        #pragma unroll
        for (int j = 0; j < 4; j++)
            bfr[j] = *(const bf16x8*)(sB + (j * 16 + l16) * 72 + ks * 32 + q * 8);
        #pragma unroll
        for (int j = 0; j < 4; j++)
            acc[j] = __builtin_amdgcn_mfma_f32_16x16x32_bf16(af, bfr[j], acc[j], 0, 0, 0);
    }

    __syncthreads();
    #pragma unroll
    for (int j = 0; j < 4; j++) {
        float bias = dtb[bn * 64 + j * 16 + l16];
        #pragma unroll
        for (int r = 0; r < 4; r++) {
            float s = acc[j][r] + bias;
            float sp = (s > 20.f) ? s : log1pf(__expf(s));
            sA[(wm + q * 4 + r) * 72 + j * 16 + l16] = f2b(sp);
        }
    }
    __syncthreads();
    int row0 = bm * 64, col0 = bn * 64;
    #pragma unroll
    for (int rep = 0; rep < 2; rep++) {
        int off = rep * 2048 + tid * 8;
        int row = off >> 6, col = off & 63;
        *(uint4*)(dtout + (size_t)(row0 + row) * D_INNER + col0 + col) =
            *(const uint4*)(sA + row * 72 + col);
    }
}

// ---------- K5a: scan pass A — lane-owns-d, 16 n-states in registers ----------
__global__ __launch_bounds__(256) void scan_partA_kernel(
    const ushort* __restrict__ dt, const ushort* __restrict__ xcq,
    const float* __restrict__ xdbl, const float* __restrict__ Alog,
    float2* __restrict__ ch1, float2* __restrict__ ch2)
{
    __shared__ float sBC[LC][32];
    int bid = blockIdx.x;
    int g = bid & 7;
    int c = (bid >> 3) & (NCH - 1);
    int b = bid >> 8;
    int tid = threadIdx.x;
    int lane = tid & 63, wid = tid >> 6;
    int d = g * 256 + wid * 64 + lane;
    int l0 = c * LC;

    {   // stage B/C tile
        int r = tid >> 3, c4 = (tid & 7) * 4;
        *(float4*)&sBC[r][c4] =
            *(const float4*)(xdbl + ((size_t)(b * LSEQ + l0 + r)) * 96 + 64 + c4);
    }
    float A[16];
    #pragma unroll
    for (int k = 0; k < 4; k++)
        *(float4*)&A[k * 4] = *(const float4*)(Alog + d * D_STATE + k * 4);
    #pragma unroll
    for (int n = 0; n < 16; n++) A[n] = -__expf(A[n]);
    __syncthreads();

    const ushort* dtp = dt  + ((size_t)(b * LSEQ + l0)) * D_INNER + d;
    const ushort* xcp = xcq + ((size_t)(b * LSEQ + l0)) * D_INNER + d;

    float h[16], ap[16];
    #pragma unroll
    for (int n = 0; n < 16; n++) { h[n] = 0.f; ap[n] = 1.f; }

    for (int l = 0; l < LC; l++) {
        float dtv = b2f(dtp[(size_t)l * D_INNER]);
        float xcv = b2f(xcp[(size_t)l * D_INNER]);
        float t = dtv * xcv;
        float Bv[16];
        #pragma unroll
        for (int k = 0; k < 4; k++)
            *(float4*)&Bv[k * 4] = *(const float4*)&sBC[l][k * 4];
        #pragma unroll
        for (int n = 0; n < 16; n++) {
            float a = __expf(dtv * A[n]);
            h[n] = h[n] * a + t * Bv[n];
            ap[n] *= a;
        }
    }

    float2* outp = (c < 16 ? ch1 : ch2) +
                   ((size_t)((b * 16 + (c & 15)) * D_INNER + d)) * D_STATE;
    #pragma unroll
    for (int n = 0; n < 16; n += 2) {
        float4 v = {ap[n], h[n], ap[n + 1], h[n + 1]};
        *(float4*)&outp[n] = v;
    }
}

// ---------- K5b: stitch (in-place: .x becomes h_init for that chunk) ----------
__global__ __launch_bounds__(256) void scan_partB_kernel(
    float2* __restrict__ ch1, float2* __restrict__ ch2)
{
    int kk = blockIdx.x * 256 + threadIdx.x;   // 65536 = b(2) x d(2048) x n(16)
    int b = kk >> 15, dn = kk & 32767;
    float run = 0.f;
    #pragma unroll
    for (int c = 0; c < NCH; c++) {
        float2* p = (c < 16 ? ch1 : ch2) +
                    (size_t)(b * 16 + (c & 15)) * 32768 + dn;
        float2 v = *p;
        p->x = run;                 // h_init entering chunk c
        run = v.x * run + v.y;
    }
}

// ---------- K5c: scan pass C — lane-owns-d, fused C-proj + D-skip + gate ----------
__global__ __launch_bounds__(256) void scan_partC_kernel(
    const ushort* __restrict__ dt, const ushort* __restrict__ xcq,
    const float* __restrict__ xdbl, const ushort* __restrict__ zq,
    const float* __restrict__ Alog, const float* __restrict__ Dp,
    const float2* __restrict__ ch1, const float2* __restrict__ ch2,
    ushort* __restrict__ yg)
{
    __shared__ float sBC[LC][32];
    int bid = blockIdx.x;
    int g = bid & 7;
    int c = (bid >> 3) & (NCH - 1);
    int b = bid >> 8;
    int tid = threadIdx.x;
    int lane = tid & 63, wid = tid >> 6;
    int d = g * 256 + wid * 64 + lane;
    int l0 = c * LC;

    {
        int r = tid >> 3, c4 = (tid & 7) * 4;
        *(float4*)&sBC[r][c4] =
            *(const float4*)(xdbl + ((size_t)(b * LSEQ + l0 + r)) * 96 + 64 + c4);
    }
    float A[16];
    #pragma unroll
    for (int k = 0; k < 4; k++)
        *(float4*)&A[k * 4] = *(const float4*)(Alog + d * D_STATE + k * 4);
    #pragma unroll
    for (int n = 0; n < 16; n++) A[n] = -__expf(A[n]);
    float Dd = Dp[d];

    const float2* hip_ = (c < 16 ? ch1 : ch2) +
                         ((size_t)((b * 16 + (c & 15)) * D_INNER + d)) * D_STATE;
    float h[16];
    #pragma unroll
    for (int n = 0; n < 16; n += 2) {
        float4 v = *(const float4*)&hip_[n];
        h[n] = v.x; h[n + 1] = v.z;
    }
    __syncthreads();

    const ushort* dtp = dt  + ((size_t)(b * LSEQ + l0)) * D_INNER + d;
    const ushort* xcp = xcq + ((size_t)(b * LSEQ + l0)) * D_INNER + d;
    const ushort* zp  = zq  + ((size_t)(b * LSEQ + l0)) * D_INNER + d;
    ushort* yp = yg + ((size_t)(b * LSEQ + l0)) * D_INNER + d;

    for (int l = 0; l < LC; l++) {
        float dtv = b2f(dtp[(size_t)l * D_INNER]);
        float xcv = b2f(xcp[(size_t)l * D_INNER]);
        float zv  = b2f(zp[(size_t)l * D_INNER]);
        float t = dtv * xcv;
        float Bv[16], Cv[16];
        #pragma unroll
        for (int k = 0; k < 4; k++) {
            *(float4*)&Bv[k * 4] = *(const float4*)&sBC[l][k * 4];
            *(float4*)&Cv[k * 4] = *(const float4*)&sBC[l][16 + k * 4];
        }
        float p0 = 0.f, p1 = 0.f, p2 = 0.f, p3 = 0.f;
        #pragma unroll
        for (int n = 0; n < 16; n += 4) {
            float a0 = __expf(dtv * A[n]);
            float a1 = __expf(dtv * A[n + 1]);
            float a2 = __expf(dtv * A[n + 2]);
            float a3 = __expf(dtv * A[n + 3]);
            h[n]     = h[n] * a0 + t * Bv[n];
            h[n + 1] = h[n + 1] * a1 + t * Bv[n + 1];
            h[n + 2] = h[n + 2] * a2 + t * Bv[n + 2];
            h[n + 3] = h[n + 3] * a3 + t * Bv[n + 3];
            p0 += h[n] * Cv[n];
            p1 += h[n + 1] * Cv[n + 1];
            p2 += h[n + 2] * Cv[n + 2];
            p3 += h[n + 3] * Cv[n + 3];
        }
        float p = (p0 + p1) + (p2 + p3);
        float y = p + Dd * xcv;
        float sz = zv / (1.f + __expf(-zv));
        yp[(size_t)l * D_INNER] = f2b(y * sz);
    }
}

extern "C" void kernel_launch(void* const* d_in, const int* in_sizes, int n_in,
                              void* d_out, int out_size, void* d_ws, size_t ws_size,
                              hipStream_t stream)
{
    const float* hs      = (const float*)d_in[0];
    const float* norm_w  = (const float*)d_in[1];
    const float* inproj  = (const float*)d_in[2];
    const float* convw   = (const float*)d_in[3];
    const float* convb   = (const float*)d_in[4];
    const float* xprojw  = (const float*)d_in[5];
    const float* dtw     = (const float*)d_in[6];
    const float* dtb     = (const float*)d_in[7];
    const float* alog    = (const float*)d_in[8];
    const float* dvec    = (const float*)d_in[9];
    const float* outproj = (const float*)d_in[10];

    float* out_main  = (float*)d_out;                        // (B,L,D_MODEL) f32
    float* out_resid = (float*)d_out + (size_t)NTOK * D_MODEL;

    // all buffers disjoint
    char* ws = (char*)d_ws;
    ushort* xq      = (ushort*)(ws);                         // 8.4MB x-half bf16
    ushort* zq      = (ushort*)(ws +  9437184);              // 8.4MB z-half bf16
    ushort* dtq     = (ushort*)(ws + 18874368);              // 8.4MB dt bf16
    float2* ch1     = (float2*)(ws + 28311552);              // 8.4MB chunks 0..15
    float2* ch2     = (float2*)(ws + 37748736);              // 8.4MB chunks 16..31
    float*  xdbl    = (float*) (ws + 47185920);              // 768KB
    ushort* xd64    = (ushort*)(ws + 48234496);              // 256KB
    ushort* xpw_b   = (ushort*)(ws + 48758784);              // 384KB
    ushort* dtw_b   = (ushort*)(ws + 49283072);              // 256KB
    ushort* wIn     = (ushort*)(ws + 50331648);              // 8.4MB
    ushort* wOut    = (ushort*)(ws + 59768832);              // 4.2MB
    ushort* h_bf16  = (ushort*)(ws + 65011712);              // 4.2MB
    float*  xprojP  = (float*) (ws + 70254592);              // 12.6MB partials
    ushort* yg_bf16 = (ushort*)(ws + 83886080);              // 8.4MB
    ushort* xcb     = (ushort*)(ws + 92274688);              // 8.4MB conv out bf16

    // K0: prep = rmsnorm + all weight conversions (one launch)
    prep_kernel<<<NTOK + 6464, 256, 0, stream>>>(
        hs, norm_w, h_bf16, out_resid,
        inproj, outproj, xprojw, dtw, wIn, wOut, xpw_b, dtw_b);

    // K2: xz GEMM -> bf16 x/z halves (async LDS staging)
    gemm_xz_kernel<<<dim3(NTOK / 128, (2 * D_INNER) / 128), 256, 0, stream>>>(
        h_bf16, wIn, xq, zq, D_MODEL);

    // K3: conv + SiLU (bf16 in/out)
    conv_silu_kernel<<<(NTOK * D_INNER) / 256, 256, 0, stream>>>(
        xq, convw, convb, xcb);

    // K4a: x_dbl GEMM — split-K partials then reduce
    xproj_partial_kernel<<<dim3(NTOK / 128, KSL), 256, 0, stream>>>(
        xcb, xpw_b, xprojP);
    xproj_reduce_kernel<<<NTOK * 96 / 256, 256, 0, stream>>>(xprojP, xdbl, xd64);

    // K4b: dt GEMM + bias + softplus -> bf16
    dt_gemm_kernel<<<dim3(NTOK / 64, D_INNER / 64), 256, 0, stream>>>(
        xd64, dtw_b, dtb, dtq);

    // K5: chunked parallel scan, lane-owns-d
    scan_partA_kernel<<<512, 256, 0, stream>>>(dtq, xcb, xdbl, alog, ch1, ch2);
    scan_partB_kernel<<<256, 256, 0, stream>>>(ch1, ch2);
    scan_partC_kernel<<<512, 256, 0, stream>>>(dtq, xcb, xdbl, zq,
                                               alog, dvec, ch1, ch2, yg_bf16);

    // K6: out = yg @ out_proj_w^T -> f32 (async LDS staging)
    gemm64_kernel<<<dim3(NTOK / 64, D_MODEL / 64), 256, 0, stream>>>(
        yg_bf16, wOut, out_main, NTOK, D_MODEL, D_INNER);
}

// Round 12
// 254.440 us; speedup vs baseline: 1.0472x; 1.0325x over previous
//
#include <hip/hip_runtime.h>

// ---------- common helpers ----------
typedef __bf16 bf16x8 __attribute__((ext_vector_type(8)));
typedef float f32x4 __attribute__((ext_vector_type(4)));

__device__ __forceinline__ float b2f(ushort u) {
    union { unsigned int i; float f; } v;
    v.i = ((unsigned int)u) << 16;
    return v.f;
}
__device__ __forceinline__ ushort f2b(float f) {
    union { float f; unsigned int i; } v;
    v.f = f;
    unsigned int x = v.i;
    unsigned int r = (x + 0x7fffu + ((x >> 16) & 1u)) >> 16;
    return (ushort)r;
}
__device__ __forceinline__ float fexp2(float x) {
#if __has_builtin(__builtin_amdgcn_exp2f)
    return __builtin_amdgcn_exp2f(x);
#else
    return exp2f(x);
#endif
}
// async 16B global->LDS; lane i lands at lds + i*16B (wave-uniform base)
__device__ __forceinline__ void gload16(const ushort* g, ushort* l) {
    __builtin_amdgcn_global_load_lds(
        (const __attribute__((address_space(1))) unsigned int*)g,
        (__attribute__((address_space(3))) unsigned int*)l, 16, 0, 0);
}
// LDS fragment read with XOR chunk swizzle (row stride 64 ushorts, 8 chunks of 8)
__device__ __forceinline__ bf16x8 ldsfrag(const ushort* s, int row, int cq) {
    int p = cq ^ (row & 7);
    return *(const bf16x8*)(s + row * 64 + p * 8);
}

#define D_MODEL 1024
#define D_INNER 2048
#define D_STATE 16
#define DT_RANK 64
#define NTOK    2048   // B*L
#define LSEQ    1024
#define NCH     64     // scan chunks
#define LC      16     // steps per chunk
#define KSL     16     // xproj K-slices
#define LOG2E   1.44269504088896f

// ---------- K0: prep = RMSNorm + weight cvts + xdbl zero ----------
__global__ __launch_bounds__(256) void prep_kernel(
    const float* __restrict__ hs, const float* __restrict__ w,
    ushort* __restrict__ hout, float* __restrict__ resid,
    const float* __restrict__ inproj, const float* __restrict__ outproj,
    const float* __restrict__ xprojw, const float* __restrict__ dtw,
    ushort* __restrict__ wIn, ushort* __restrict__ wOut,
    ushort* __restrict__ xpw, ushort* __restrict__ dtwb,
    float* __restrict__ xdbl)
{
    int blk = blockIdx.x;
    int tid = threadIdx.x;
    if (blk < NTOK) {
        int t = blk;
        float4 r4 = *(const float4*)(hs + (size_t)t * D_MODEL + tid * 4);
        float s = r4.x * r4.x + r4.y * r4.y + r4.z * r4.z + r4.w * r4.w;
        #pragma unroll
        for (int off = 32; off >= 1; off >>= 1) s += __shfl_xor(s, off);
        __shared__ float red[4];
        int lane = tid & 63, wid = tid >> 6;
        if (lane == 0) red[wid] = s;
        __syncthreads();
        float tot = red[0] + red[1] + red[2] + red[3];
        float inv = 1.0f / (sqrtf(tot) * (1.0f / 32.0f) + 1e-5f);
        float4 w4 = *(const float4*)(w + tid * 4);
        ushort4 o;
        o.x = f2b(w4.x * r4.x * inv);
        o.y = f2b(w4.y * r4.y * inv);
        o.z = f2b(w4.z * r4.z * inv);
        o.w = f2b(w4.w * r4.w * inv);
        *(ushort4*)(hout + (size_t)t * D_MODEL + tid * 4) = o;
        *(float4*)(resid + (size_t)t * D_MODEL + tid * 4) = r4;   // exact copy
    } else if (blk < NTOK + 6464) {
        int i = (blk - NTOK) * 256 + tid;
        const float* src; ushort* dst; int off;
        if (i < 1048576)      { src = inproj;  dst = wIn;  off = i; }
        else if (i < 1572864) { src = outproj; dst = wOut; off = i - 1048576; }
        else if (i < 1622016) { src = xprojw;  dst = xpw;  off = i - 1572864; }
        else if (i < 1654784) { src = dtw;     dst = dtwb; off = i - 1622016; }
        else return;
        float4 v = *(const float4*)(src + (size_t)off * 4);
        ushort4 o;
        o.x = f2b(v.x); o.y = f2b(v.y); o.z = f2b(v.z); o.w = f2b(v.w);
        *(ushort4*)(dst + (size_t)off * 4) = o;
    } else {
        int i = (blk - NTOK - 6464) * 256 + tid;   // 49152 float4s = 196608 floats
        if (i < 49152)
            *(float4*)(xdbl + (size_t)i * 4) = (float4){0.f, 0.f, 0.f, 0.f};
    }
}

// ---------- K2: xz GEMM 128x128, BK=64, async global_load_lds + XOR swizzle ----------
__global__ __launch_bounds__(256) void gemm_xz_kernel(
    const ushort* __restrict__ Ag, const ushort* __restrict__ Wg,
    ushort* __restrict__ xq, ushort* __restrict__ zq, int K)
{
    __shared__ __align__(16) ushort sA[128 * 64];
    __shared__ __align__(16) ushort sB[128 * 64];
    int tid = threadIdx.x;
    int bm = blockIdx.x, bn = blockIdx.y;
    int wid = tid >> 6, lane = tid & 63;
    int wm = (wid >> 1) * 64, wn = (wid & 1) * 64;
    int l16 = lane & 15, q = lane >> 4;

    f32x4 acc[4][4];
    #pragma unroll
    for (int i = 0; i < 4; i++)
        #pragma unroll
        for (int j = 0; j < 4; j++)
            acc[i][j] = (f32x4){0.f, 0.f, 0.f, 0.f};

    const ushort* Abase = Ag + (size_t)bm * 128 * K;
    const ushort* Wbase = Wg + (size_t)bn * 128 * K;

    int segr = lane >> 3, segc = lane & 7;
    size_t goff[4]; int sseg[4];
    #pragma unroll
    for (int t = 0; t < 4; t++) {
        int s = wid * 4 + t;
        int r = s * 8 + segr;
        int gc = segc ^ (r & 7);
        sseg[t] = s * 512;
        goff[t] = (size_t)r * K + gc * 8;
    }

    for (int k0 = 0; k0 < K; k0 += 64) {
        __syncthreads();
        #pragma unroll
        for (int t = 0; t < 4; t++) {
            gload16(Abase + goff[t] + k0, sA + sseg[t]);
            gload16(Wbase + goff[t] + k0, sB + sseg[t]);
        }
        __syncthreads();
        #pragma unroll
        for (int ks = 0; ks < 2; ks++) {
            int cq = ks * 4 + q;
            bf16x8 af[4], bfr[4];
            #pragma unroll
            for (int i = 0; i < 4; i++)
                af[i] = ldsfrag(sA, wm + i * 16 + l16, cq);
            #pragma unroll
            for (int j = 0; j < 4; j++)
                bfr[j] = ldsfrag(sB, wn + j * 16 + l16, cq);
            #pragma unroll
            for (int i = 0; i < 4; i++)
                #pragma unroll
                for (int j = 0; j < 4; j++)
                    acc[i][j] = __builtin_amdgcn_mfma_f32_16x16x32_bf16(af[i], bfr[j], acc[i][j], 0, 0, 0);
        }
    }

    ushort* dst = (bn < 16) ? xq : zq;
    int row0 = bm * 128 + wm + q * 4;
    int col0 = (bn & 15) * 128 + wn + l16;
    #pragma unroll
    for (int i = 0; i < 4; i++)
        #pragma unroll
        for (int j = 0; j < 4; j++)
            #pragma unroll
            for (int r = 0; r < 4; r++)
                dst[(size_t)(row0 + i * 16 + r) * D_INNER + col0 + j * 16] =
                    f2b(acc[i][j][r]);
}

// ---------- K6: 64x64 GEMM, BK=64, async + XOR swizzle ----------
__global__ __launch_bounds__(256) void gemm64_kernel(
    const ushort* __restrict__ Ag, const ushort* __restrict__ Wg,
    float* __restrict__ Cf, int M, int N, int K)
{
    __shared__ __align__(16) ushort sA[64 * 64];
    __shared__ __align__(16) ushort sB[64 * 64];
    int tid = threadIdx.x;
    int bm = blockIdx.x, bn = blockIdx.y;
    int wid = tid >> 6, lane = tid & 63;
    int wm = wid * 16;
    int l16 = lane & 15, q = lane >> 4;

    f32x4 acc[4];
    #pragma unroll
    for (int j = 0; j < 4; j++) acc[j] = (f32x4){0.f, 0.f, 0.f, 0.f};

    const ushort* Abase = Ag + (size_t)bm * 64 * K;
    const ushort* Wbase = Wg + (size_t)bn * 64 * K;

    int segr = lane >> 3, segc = lane & 7;
    size_t goff[2]; int sseg[2];
    #pragma unroll
    for (int t = 0; t < 2; t++) {
        int s = wid * 2 + t;
        int r = s * 8 + segr;
        int gc = segc ^ (r & 7);
        sseg[t] = s * 512;
        goff[t] = (size_t)r * K + gc * 8;
    }

    for (int k0 = 0; k0 < K; k0 += 64) {
        __syncthreads();
        #pragma unroll
        for (int t = 0; t < 2; t++) {
            gload16(Abase + goff[t] + k0, sA + sseg[t]);
            gload16(Wbase + goff[t] + k0, sB + sseg[t]);
        }
        __syncthreads();
        #pragma unroll
        for (int ks = 0; ks < 2; ks++) {
            int cq = ks * 4 + q;
            bf16x8 af = ldsfrag(sA, wm + l16, cq);
            bf16x8 bfr[4];
            #pragma unroll
            for (int j = 0; j < 4; j++)
                bfr[j] = ldsfrag(sB, j * 16 + l16, cq);
            #pragma unroll
            for (int j = 0; j < 4; j++)
                acc[j] = __builtin_amdgcn_mfma_f32_16x16x32_bf16(af, bfr[j], acc[j], 0, 0, 0);
        }
    }

    int row0 = bm * 64 + wm + q * 4;
    int col0 = bn * 64 + l16;
    #pragma unroll
    for (int j = 0; j < 4; j++)
        #pragma unroll
        for (int r = 0; r < 4; r++)
            Cf[(size_t)(row0 + r) * N + col0 + j * 16] = acc[j][r];
}

// ---------- K3: causal depthwise conv (4 taps) + SiLU, bf16 in/out ----------
__global__ __launch_bounds__(256) void conv_silu_kernel(
    const ushort* __restrict__ xq, const float* __restrict__ cw,
    const float* __restrict__ cb, ushort* __restrict__ xcb)
{
    int idx = blockIdx.x * 256 + threadIdx.x;
    int d = idx & (D_INNER - 1);
    int t = idx >> 11;
    int l = t & (LSEQ - 1), b = t >> 10;
    float4 w4 = *(const float4*)(cw + d * 4);
    float acc = cb[d];
    float wk[4] = {w4.x, w4.y, w4.z, w4.w};
    #pragma unroll
    for (int k = 0; k < 4; k++) {
        int ll = l - 3 + k;
        float xv = (ll >= 0) ? b2f(xq[(((size_t)(b * LSEQ + ll)) << 11) + d]) : 0.f;
        acc += xv * wk[k];
    }
    float sg = acc / (1.f + __expf(-acc));
    xcb[idx] = f2b(sg);
}

// ---------- K4a: xproj split-K partial GEMM, atomic accumulate into xdbl ----------
__global__ __launch_bounds__(256) void xproj_partial_kernel(
    const ushort* __restrict__ xcb, const ushort* __restrict__ wq,
    float* __restrict__ xdbl)
{
    __shared__ __align__(16) ushort sA[128 * 32];
    __shared__ __align__(16) ushort sB[96 * 32];
    int tid = threadIdx.x;
    int bm = blockIdx.x, sl = blockIdx.y;
    int wid = tid >> 6, lane = tid & 63;
    int wm = wid * 32;
    int l16 = lane & 15, q = lane >> 4;

    f32x4 acc[2][6];
    #pragma unroll
    for (int i = 0; i < 2; i++)
        #pragma unroll
        for (int j = 0; j < 6; j++)
            acc[i][j] = (f32x4){0.f, 0.f, 0.f, 0.f};

    const ushort* Abase = xcb + (size_t)bm * 128 * D_INNER;
    int kbase = sl * (D_INNER / KSL);

    for (int kk = 0; kk < D_INNER / KSL; kk += 32) {
        int k0 = kbase + kk;
        __syncthreads();
        #pragma unroll
        for (int i = tid; i < 512; i += 256) {
            int r = i >> 2, c = (i & 3) << 3;
            *(uint4*)(sA + i * 8) = *(const uint4*)(Abase + (size_t)r * D_INNER + k0 + c);
        }
        for (int i = tid; i < 384; i += 256) {
            int r = i >> 2, c = (i & 3) << 3;
            *(uint4*)(sB + i * 8) = *(const uint4*)(wq + (size_t)r * D_INNER + k0 + c);
        }
        __syncthreads();
        bf16x8 af[2], bfr[6];
        #pragma unroll
        for (int i = 0; i < 2; i++)
            af[i] = *(const bf16x8*)(sA + (wm + i * 16 + l16) * 32 + q * 8);
        #pragma unroll
        for (int j = 0; j < 6; j++)
            bfr[j] = *(const bf16x8*)(sB + (j * 16 + l16) * 32 + q * 8);
        #pragma unroll
        for (int i = 0; i < 2; i++)
            #pragma unroll
            for (int j = 0; j < 6; j++)
                acc[i][j] = __builtin_amdgcn_mfma_f32_16x16x32_bf16(af[i], bfr[j], acc[i][j], 0, 0, 0);
    }

    int row0 = bm * 128 + wm + q * 4;
    #pragma unroll
    for (int i = 0; i < 2; i++)
        #pragma unroll
        for (int j = 0; j < 6; j++)
            #pragma unroll
            for (int r = 0; r < 4; r++)
                atomicAdd(&xdbl[(size_t)(row0 + i * 16 + r) * 96 + j * 16 + l16],
                          acc[i][j][r]);
}

// ---------- K4b: dt = softplus(xdbl[:, :64] @ dt_proj_w^T + b) -> bf16 ----------
__global__ __launch_bounds__(256) void dt_gemm_kernel(
    const float* __restrict__ xdbl, const ushort* __restrict__ dtwq,
    const float* __restrict__ dtb, ushort* __restrict__ dtout)
{
    __shared__ __align__(16) ushort sA[64 * 72];
    __shared__ __align__(16) ushort sB[64 * 72];
    int tid = threadIdx.x;
    int bm = blockIdx.x, bn = blockIdx.y;
    int wid = tid >> 6, lane = tid & 63;
    int wm = wid * 16;
    int l16 = lane & 15, q = lane >> 4;

    const float* Abase = xdbl + (size_t)bm * 64 * 96;
    const ushort* Bbase = dtwq + (size_t)bn * 64 * DT_RANK;
    #pragma unroll
    for (int i = tid; i < 512; i += 256) {
        int r = i >> 3, c = (i & 7) << 3;
        float4 v0 = *(const float4*)(Abase + (size_t)r * 96 + c);
        float4 v1 = *(const float4*)(Abase + (size_t)r * 96 + c + 4);
        ushort o[8] = {f2b(v0.x), f2b(v0.y), f2b(v0.z), f2b(v0.w),
                       f2b(v1.x), f2b(v1.y), f2b(v1.z), f2b(v1.w)};
        *(uint4*)(sA + r * 72 + c) = *(const uint4*)o;
        *(uint4*)(sB + r * 72 + c) = *(const uint4*)(Bbase + (size_t)r * DT_RANK + c);
    }
    __syncthreads();

    f32x4 acc[4];
    #pragma unroll
    for (int j = 0; j < 4; j++) acc[j] = (f32x4){0.f, 0.f, 0.f, 0.f};

    #pragma unroll
    for (int ks = 0; ks < 2; ks++) {
        bf16x8 af = *(const bf16x8*)(sA + (wm + l16) * 72 + ks * 32 + q * 8);
        bf16x8 bfr[4];
        #pragma unroll
        for (int j = 0; j < 4; j++)
            bfr[j] = *(const bf16x8*)(sB + (j * 16 + l16) * 72 + ks * 32 + q * 8);
        #pragma unroll
        for (int j = 0; j < 4; j++)
            acc[j] = __builtin_amdgcn_mfma_f32_16x16x32_bf16(af, bfr[j], acc[j], 0, 0, 0);
    }

    __syncthreads();
    #pragma unroll
    for (int j = 0; j < 4; j++) {
        float bias = dtb[bn * 64 + j * 16 + l16];
        #pragma unroll
        for (int r = 0; r < 4; r++) {
            float s = acc[j][r] + bias;
            float sp = (s > 20.f) ? s : log1pf(__expf(s));
            sA[(wm + q * 4 + r) * 72 + j * 16 + l16] = f2b(sp);
        }
    }
    __syncthreads();
    int row0 = bm * 64, col0 = bn * 64;
    #pragma unroll
    for (int rep = 0; rep < 2; rep++) {
        int off = rep * 2048 + tid * 8;
        int row = off >> 6, col = off & 63;
        *(uint4*)(dtout + (size_t)(row0 + row) * D_INNER + col0 + col) =
            *(const uint4*)(sA + row * 72 + col);
    }
}

// ---------- K5a: scan pass A — lane-owns-d, NCH=64 ----------
__global__ __launch_bounds__(256) void scan_partA_kernel(
    const ushort* __restrict__ dt, const ushort* __restrict__ xcq,
    const float* __restrict__ xdbl, const float* __restrict__ Alog,
    float2* __restrict__ ch)
{
    __shared__ float sBC[LC][32];
    int bid = blockIdx.x;                  // 1024 = b(2) x chunk(64) x dgroup(8)
    int g = bid & 7;
    int c = (bid >> 3) & (NCH - 1);
    int b = bid >> 9;
    int tid = threadIdx.x;
    int lane = tid & 63, wid = tid >> 6;
    int d = g * 256 + wid * 64 + lane;
    int l0 = c * LC;

    if (tid < LC * 8) {                    // stage B/C tile (16 rows x 32 floats)
        int r = tid >> 3, c4 = (tid & 7) * 4;
        *(float4*)&sBC[r][c4] =
            *(const float4*)(xdbl + ((size_t)(b * LSEQ + l0 + r)) * 96 + 64 + c4);
    }
    float A[16];
    #pragma unroll
    for (int k = 0; k < 4; k++)
        *(float4*)&A[k * 4] = *(const float4*)(Alog + d * D_STATE + k * 4);
    #pragma unroll
    for (int n = 0; n < 16; n++) A[n] = -__expf(A[n]) * LOG2E;
    __syncthreads();

    const ushort* dtp = dt  + ((size_t)(b * LSEQ + l0)) * D_INNER + d;
    const ushort* xcp = xcq + ((size_t)(b * LSEQ + l0)) * D_INNER + d;

    float h[16], ap[16];
    #pragma unroll
    for (int n = 0; n < 16; n++) { h[n] = 0.f; ap[n] = 1.f; }

    for (int l = 0; l < LC; l++) {
        float dtv = b2f(dtp[(size_t)l * D_INNER]);
        float xcv = b2f(xcp[(size_t)l * D_INNER]);
        float t = dtv * xcv;
        float Bv[16];
        #pragma unroll
        for (int k = 0; k < 4; k++)
            *(float4*)&Bv[k * 4] = *(const float4*)&sBC[l][k * 4];
        #pragma unroll
        for (int n = 0; n < 16; n++) {
            float a = fexp2(dtv * A[n]);
            h[n] = h[n] * a + t * Bv[n];
            ap[n] *= a;
        }
    }

    float2* outp = ch + (((size_t)(c * 2 + b)) << 15) + (d << 4);
    #pragma unroll
    for (int n = 0; n < 16; n += 2) {
        float4 v = {ap[n], h[n], ap[n + 1], h[n + 1]};
        *(float4*)&outp[n] = v;
    }
}

// ---------- K5b: stitch (in-place: .x becomes h_init) ----------
__global__ __launch_bounds__(256) void scan_partB_kernel(float2* __restrict__ ch)
{
    int kk = blockIdx.x * 256 + threadIdx.x;   // 65536 = b(2) x dn(32768)
    int b = kk >> 15, dn = kk & 32767;
    float run = 0.f;
    #pragma unroll 8
    for (int c = 0; c < NCH; c++) {
        float2* p = ch + (((size_t)(c * 2 + b)) << 15) + dn;
        float2 v = *p;
        p->x = run;
        run = v.x * run + v.y;
    }
}

// ---------- K5c: scan pass C — lane-owns-d, fused C-proj + D-skip + gate ----------
__global__ __launch_bounds__(256) void scan_partC_kernel(
    const ushort* __restrict__ dt, const ushort* __restrict__ xcq,
    const float* __restrict__ xdbl, const ushort* __restrict__ zq,
    const float* __restrict__ Alog, const float* __restrict__ Dp,
    const float2* __restrict__ ch, ushort* __restrict__ yg)
{
    __shared__ float sBC[LC][32];
    int bid = blockIdx.x;
    int g = bid & 7;
    int c = (bid >> 3) & (NCH - 1);
    int b = bid >> 9;
    int tid = threadIdx.x;
    int lane = tid & 63, wid = tid >> 6;
    int d = g * 256 + wid * 64 + lane;
    int l0 = c * LC;

    if (tid < LC * 8) {
        int r = tid >> 3, c4 = (tid & 7) * 4;
        *(float4*)&sBC[r][c4] =
            *(const float4*)(xdbl + ((size_t)(b * LSEQ + l0 + r)) * 96 + 64 + c4);
    }
    float A[16];
    #pragma unroll
    for (int k = 0; k < 4; k++)
        *(float4*)&A[k * 4] = *(const float4*)(Alog + d * D_STATE + k * 4);
    #pragma unroll
    for (int n = 0; n < 16; n++) A[n] = -__expf(A[n]) * LOG2E;
    float Dd = Dp[d];

    const float2* hip_ = ch + (((size_t)(c * 2 + b)) << 15) + (d << 4);
    float h[16];
    #pragma unroll
    for (int n = 0; n < 16; n += 2) {
        float4 v = *(const float4*)&hip_[n];
        h[n] = v.x; h[n + 1] = v.z;
    }
    __syncthreads();

    const ushort* dtp = dt  + ((size_t)(b * LSEQ + l0)) * D_INNER + d;
    const ushort* xcp = xcq + ((size_t)(b * LSEQ + l0)) * D_INNER + d;
    const ushort* zp  = zq  + ((size_t)(b * LSEQ + l0)) * D_INNER + d;
    ushort* yp = yg + ((size_t)(b * LSEQ + l0)) * D_INNER + d;

    for (int l = 0; l < LC; l++) {
        float dtv = b2f(dtp[(size_t)l * D_INNER]);
        float xcv = b2f(xcp[(size_t)l * D_INNER]);
        float zv  = b2f(zp[(size_t)l * D_INNER]);
        float t = dtv * xcv;
        float Bv[16], Cv[16];
        #pragma unroll
        for (int k = 0; k < 4; k++) {
            *(float4*)&Bv[k * 4] = *(const float4*)&sBC[l][k * 4];
            *(float4*)&Cv[k * 4] = *(const float4*)&sBC[l][16 + k * 4];
        }
        float p0 = 0.f, p1 = 0.f, p2 = 0.f, p3 = 0.f;
        #pragma unroll
        for (int n = 0; n < 16; n += 4) {
            float a0 = fexp2(dtv * A[n]);
            float a1 = fexp2(dtv * A[n + 1]);
            float a2 = fexp2(dtv * A[n + 2]);
            float a3 = fexp2(dtv * A[n + 3]);
            h[n]     = h[n] * a0 + t * Bv[n];
            h[n + 1] = h[n + 1] * a1 + t * Bv[n + 1];
            h[n + 2] = h[n + 2] * a2 + t * Bv[n + 2];
            h[n + 3] = h[n + 3] * a3 + t * Bv[n + 3];
            p0 += h[n] * Cv[n];
            p1 += h[n + 1] * Cv[n + 1];
            p2 += h[n + 2] * Cv[n + 2];
            p3 += h[n + 3] * Cv[n + 3];
        }
        float p = (p0 + p1) + (p2 + p3);
        float y = p + Dd * xcv;
        float sz = zv / (1.f + __expf(-zv));
        yp[(size_t)l * D_INNER] = f2b(y * sz);
    }
}

extern "C" void kernel_launch(void* const* d_in, const int* in_sizes, int n_in,
                              void* d_out, int out_size, void* d_ws, size_t ws_size,
                              hipStream_t stream)
{
    const float* hs      = (const float*)d_in[0];
    const float* norm_w  = (const float*)d_in[1];
    const float* inproj  = (const float*)d_in[2];
    const float* convw   = (const float*)d_in[3];
    const float* convb   = (const float*)d_in[4];
    const float* xprojw  = (const float*)d_in[5];
    const float* dtw     = (const float*)d_in[6];
    const float* dtb     = (const float*)d_in[7];
    const float* alog    = (const float*)d_in[8];
    const float* dvec    = (const float*)d_in[9];
    const float* outproj = (const float*)d_in[10];

    float* out_main  = (float*)d_out;
    float* out_resid = (float*)d_out + (size_t)NTOK * D_MODEL;

    char* ws = (char*)d_ws;
    ushort* xq      = (ushort*)(ws);                         // 8.4MB
    ushort* zq      = (ushort*)(ws +  8388608);              // 8.4MB
    ushort* dtq     = (ushort*)(ws + 16777216);              // 8.4MB
    ushort* xcb     = (ushort*)(ws + 25165824);              // 8.4MB
    float2* ch      = (float2*)(ws + 33554432);              // 33.6MB (64 chunks)
    float*  xdbl    = (float*) (ws + 67108864);              // 768KB
    ushort* wIn     = (ushort*)(ws + 67895296);              // 8.4MB
    ushort* wOut    = (ushort*)(ws + 76283904);              // 4.2MB
    ushort* h_bf16  = (ushort*)(ws + 80478208);              // 4.2MB
    ushort* xpw_b   = (ushort*)(ws + 84672512);              // 384KB
    ushort* dtw_b   = (ushort*)(ws + 85065728);              // 256KB
    ushort* yg_bf16 = (ushort*)(ws + 85327872);              // 8.4MB  (end ~93.7MB)

    // K0: prep = rmsnorm + weight cvts + xdbl zero (2048 + 6464 + 192 blocks)
    prep_kernel<<<NTOK + 6464 + 192, 256, 0, stream>>>(
        hs, norm_w, h_bf16, out_resid,
        inproj, outproj, xprojw, dtw, wIn, wOut, xpw_b, dtw_b, xdbl);

    // K2: xz GEMM -> bf16 x/z halves
    gemm_xz_kernel<<<dim3(NTOK / 128, (2 * D_INNER) / 128), 256, 0, stream>>>(
        h_bf16, wIn, xq, zq, D_MODEL);

    // K3: conv + SiLU
    conv_silu_kernel<<<(NTOK * D_INNER) / 256, 256, 0, stream>>>(
        xq, convw, convb, xcb);

    // K4a: x_dbl GEMM — split-K, atomic accumulate into zeroed xdbl
    xproj_partial_kernel<<<dim3(NTOK / 128, KSL), 256, 0, stream>>>(
        xcb, xpw_b, xdbl);

    // K4b: dt GEMM (A staged from f32 xdbl) + bias + softplus -> bf16
    dt_gemm_kernel<<<dim3(NTOK / 64, D_INNER / 64), 256, 0, stream>>>(
        xdbl, dtw_b, dtb, dtq);

    // K5: chunked parallel scan, NCH=64 (4 blocks/CU)
    scan_partA_kernel<<<1024, 256, 0, stream>>>(dtq, xcb, xdbl, alog, ch);
    scan_partB_kernel<<<256, 256, 0, stream>>>(ch);
    scan_partC_kernel<<<1024, 256, 0, stream>>>(dtq, xcb, xdbl, zq,
                                                alog, dvec, ch, yg_bf16);

    // K6: out = yg @ out_proj_w^T -> f32
    gemm64_kernel<<<dim3(NTOK / 64, D_MODEL / 64), 256, 0, stream>>>(
        yg_bf16, wOut, out_main, NTOK, D_MODEL, D_INNER);
}